// Round 4
// baseline (376.812 us; speedup 1.0000x reference)
//
#include <hip/hip_runtime.h>
#include <stdint.h>

#define B_  16
#define C_  512
#define S_  1024
#define NSAMP (C_*S_)

typedef __bf16 bf16x8 __attribute__((ext_vector_type(8)));
typedef float  f32x4  __attribute__((ext_vector_type(4)));

__device__ __forceinline__ float bf2f(uint16_t u){ return __uint_as_float(((uint32_t)u)<<16); }
__device__ __forceinline__ uint16_t f2bf(float f){
  uint32_t u = __float_as_uint(f);
  uint32_t r = u + 0x7fffu + ((u>>16)&1u);   // RNE
  return (uint16_t)(r>>16);
}
__device__ __forceinline__ float wsum(float v){
  #pragma unroll
  for(int o=32;o;o>>=1) v += __shfl_xor(v,o,64);
  return v;
}
__device__ __forceinline__ void gload16(const void* g, void* l){
  __builtin_amdgcn_global_load_lds(
      (__attribute__((address_space(1))) void*)g,
      (__attribute__((address_space(3))) void*)l, 16, 0, 0);
}

// ---------- dtype detector ----------
__global__ __launch_bounds__(256) void detect_k(const uint16_t* __restrict__ x,
                                                int* __restrict__ flag){
  __shared__ int sh[4];
  int cnt = 0;
  for(int i=threadIdx.x; i<32768; i+=256){
    uint32_t e = (x[2*i] >> 7) & 0xffu;
    cnt += (e >= 132) ? 1 : 0;
  }
  #pragma unroll
  for(int o=32;o;o>>=1) cnt += __shfl_xor(cnt,o,64);
  const int lane = threadIdx.x & 63, w = threadIdx.x >> 6;
  if (lane==0) sh[w] = cnt;
  __syncthreads();
  if (threadIdx.x==0) *flag = (sh[0]+sh[1]+sh[2]+sh[3] > 4096) ? 1 : 0;  // 1 => fp32
}

// ---------- fused: x -> bf16 copy + GN partial sums ----------
__global__ __launch_bounds__(256) void conv_x_gn(const void* __restrict__ src,
                                                 uint16_t* __restrict__ xb,
                                                 float2* __restrict__ part,
                                                 const int* __restrict__ flag){
  const int f = *flag;
  const size_t base = (size_t)blockIdx.x * 8192;
  float s = 0.f, s2 = 0.f;
  if (f){
    const float4* sp = (const float4*)((const float*)src + base);
    ushort4* dp = (ushort4*)(xb + base);
    #pragma unroll
    for(int i=0;i<8;i++){
      float4 v = sp[i*256 + threadIdx.x];
      s  += v.x + v.y + v.z + v.w;
      s2 += v.x*v.x + v.y*v.y + v.z*v.z + v.w*v.w;
      ushort4 o; o.x=f2bf(v.x); o.y=f2bf(v.y); o.z=f2bf(v.z); o.w=f2bf(v.w);
      dp[i*256 + threadIdx.x] = o;
    }
  } else {
    const uint4* sp = (const uint4*)((const uint16_t*)src + base);
    uint4* dp = (uint4*)(xb + base);
    #pragma unroll
    for(int i=0;i<4;i++){
      uint4 p = sp[i*256 + threadIdx.x];
      dp[i*256 + threadIdx.x] = p;
      uint32_t uu[4] = {p.x,p.y,p.z,p.w};
      #pragma unroll
      for(int q=0;q<4;q++){
        float f0 = __uint_as_float(uu[q]<<16);
        float f1 = __uint_as_float(uu[q] & 0xffff0000u);
        s += f0 + f1; s2 += f0*f0 + f1*f1;
      }
    }
  }
  s = wsum(s); s2 = wsum(s2);
  __shared__ float rs[4], rq[4];
  const int lane = threadIdx.x & 63, w = threadIdx.x >> 6;
  if (lane==0){ rs[w]=s; rq[w]=s2; }
  __syncthreads();
  if (threadIdx.x==0)
    part[blockIdx.x] = make_float2(rs[0]+rs[1]+rs[2]+rs[3], rq[0]+rq[1]+rq[2]+rq[3]);
}

// ---------- all params -> bf16 copies ----------
__device__ __forceinline__ void convseg(const void* src, uint16_t* dst, int n, int f, int t){
  const int idx = t*8;
  if (idx >= n) return;
  if (f){
    const float* s = (const float*)src;
    float4 v0 = *(const float4*)(s + idx);
    float4 v1 = *(const float4*)(s + idx + 4);
    ushort4 a, b;
    a.x=f2bf(v0.x); a.y=f2bf(v0.y); a.z=f2bf(v0.z); a.w=f2bf(v0.w);
    b.x=f2bf(v1.x); b.y=f2bf(v1.y); b.z=f2bf(v1.z); b.w=f2bf(v1.w);
    *(ushort4*)(dst + idx)     = a;
    *(ushort4*)(dst + idx + 4) = b;
  } else {
    *(uint4*)(dst + idx) = *(const uint4*)((const uint16_t*)src + idx);
  }
}
__global__ __launch_bounds__(256) void param_conv(
    const void* qkvw, const void* projw, const void* gnw, const void* gnb,
    const void* qkvb, const void* projb,
    uint16_t* qkvwb, uint16_t* projwb, uint16_t* gnwb, uint16_t* gnbb,
    uint16_t* qkvbb, uint16_t* projbb, const int* __restrict__ flag){
  const int f = *flag;
  const int bid = blockIdx.x, t = threadIdx.x;
  if (bid < 384){
    const size_t off = (size_t)bid*2048;
    convseg((const char*)qkvw + off*(f?4:2), qkvwb + off, 2048, f, t);
  } else if (bid < 512){
    const size_t off = (size_t)(bid-384)*2048;
    convseg((const char*)projw + off*(f?4:2), projwb + off, 2048, f, t);
  } else {
    convseg(gnw,   gnwb,   512,  f, t);
    convseg(gnb,   gnbb,   512,  f, t);
    convseg(qkvb,  qkvbb,  1536, f, t);
    convseg(projb, projbb, 512,  f, t);
  }
}

// ---- GN apply + transpose [B,C,S] -> hT [B,S,C] bf16 ----
__global__ __launch_bounds__(256) void gn_apply_t(const uint16_t* __restrict__ x,
    const uint16_t* __restrict__ gw, const uint16_t* __restrict__ gb,
    const float2* __restrict__ part, uint16_t* __restrict__ hT){
  __shared__ float tile[64][65];
  const int b = blockIdx.z, c0 = blockIdx.y<<6, s0 = blockIdx.x<<6;
  const int tc = threadIdx.x >> 6, tl = threadIdx.x & 63;
  float2 p = part[b*64 + tl];
  float s = wsum(p.x), s2 = wsum(p.y);
  const float ninv = 1.f/(float)NSAMP;
  const float mn = s*ninv;
  const float rstd = rsqrtf(s2*ninv - mn*mn + 1e-5f);
  #pragma unroll
  for(int r=0;r<16;r++){
    int cl = r*4 + tc;
    tile[cl][tl] = bf2f(x[((size_t)b*C_ + c0+cl)*S_ + s0 + tl]);
  }
  __syncthreads();
  const float wv = bf2f(gw[c0+tl]) * rstd;
  const float bv = bf2f(gb[c0+tl]);
  #pragma unroll
  for(int r=0;r<16;r++){
    int sl = r*4 + tc;
    float v = (tile[tl][sl] - mn)*wv + bv;
    hT[((size_t)b*S_ + s0+sl)*C_ + c0 + tl] = f2bf(v);
  }
}

// ---------------- 128x128 MFMA GEMM, C = A * Bt^T, XCD-swizzled ----------------
template<bool HASBIAS, bool BIASROW, bool OUTDYN, bool HASRES>
__global__ __launch_bounds__(256)
void gemm_bt(const uint16_t* __restrict__ A, const uint16_t* __restrict__ Bt,
             void* __restrict__ Cp, const uint16_t* __restrict__ bias,
             const uint16_t* __restrict__ xres, const int* __restrict__ flag,
             int lda, int ldb, int ldc, int K,
             long long sA, long long sB, long long sC)
{
  __shared__ uint16_t As[128*64];
  __shared__ uint16_t Bs[128*64];
  const int lin = (blockIdx.z * gridDim.y + blockIdx.y) * gridDim.x + blockIdx.x;
  const int xcd = lin & 7, t = lin >> 3;
  const int bx  = t % gridDim.x;
  const int rr  = (t / gridDim.x) * 8 + xcd;
  const int by  = rr % gridDim.y;
  const int bz  = rr / gridDim.y;

  const int tid = threadIdx.x;
  const int lane = tid & 63, w = tid >> 6;
  const int quad = lane >> 4, lm = lane & 15;
  const int m0 = by << 7, n0 = bx << 7;
  A  += (size_t)bz * sA;
  Bt += (size_t)bz * sB;

  f32x4 acc[4][4];
  #pragma unroll
  for(int i=0;i<4;i++)
    #pragma unroll
    for(int j=0;j<4;j++) acc[i][j] = (f32x4){0.f,0.f,0.f,0.f};

  const int wm = (w & 1) << 6, wn = (w >> 1) << 6;
  const uint16_t* ga = A  + (size_t)(m0 + (tid>>3))*lda + (tid&7)*8;
  const uint16_t* gb = Bt + (size_t)(n0 + (tid>>3))*ldb + (tid&7)*8;
  uint16_t* sa = &As[tid*8];
  uint16_t* sb = &Bs[tid*8];

  for(int k0=0;k0<K;k0+=64){
    #pragma unroll
    for(int i=0;i<4;i++){
      gload16(ga + (size_t)(i*32)*lda + k0, sa + i*2048);
      gload16(gb + (size_t)(i*32)*ldb + k0, sb + i*2048);
    }
    __syncthreads();
    #pragma unroll
    for(int kk=0;kk<64;kk+=32){
      bf16x8 av[4], bv[4];
      #pragma unroll
      for(int i=0;i<4;i++) av[i] = *(const bf16x8*)&As[(wm + i*16 + lm)*64 + kk + quad*8];
      #pragma unroll
      for(int j=0;j<4;j++) bv[j] = *(const bf16x8*)&Bs[(wn + j*16 + lm)*64 + kk + quad*8];
      #pragma unroll
      for(int i=0;i<4;i++)
        #pragma unroll
        for(int j=0;j<4;j++)
          acc[i][j] = __builtin_amdgcn_mfma_f32_16x16x32_bf16(av[i], bv[j], acc[i][j], 0,0,0);
    }
    __syncthreads();
  }

  const int f = OUTDYN ? *flag : 0;
  const size_t cb = (size_t)bz * (size_t)sC;
  #pragma unroll
  for(int j=0;j<4;j++){
    const int col = n0 + wn + j*16 + lm;
    const float cbias = (HASBIAS && !BIASROW) ? bf2f(bias[col]) : 0.f;
    #pragma unroll
    for(int i=0;i<4;i++){
      const int rb = m0 + wm + i*16 + (quad<<2);
      #pragma unroll
      for(int r=0;r<4;r++){
        const int row = rb + r;
        float v = acc[i][j][r] + cbias;
        if (HASBIAS && BIASROW) v += bf2f(bias[row]);
        const size_t idx = cb + (size_t)row*ldc + col;
        if (HASRES) v += bf2f(xres[idx]);
        if (OUTDYN && f) ((float*)Cp)[idx] = v;
        else             ((uint16_t*)Cp)[idx] = f2bf(v);
      }
    }
  }
}

// ======== fused attention: per block = 32 Q-rows of one batch; exact softmax ========
// S = Q·K^T (fp32 regs, 32x1024) -> softmax block-local -> P(bf16, LDS) -> O = P·V
__global__ __launch_bounds__(256, 1)
void attn_fused(const uint16_t* __restrict__ qk, const uint16_t* __restrict__ Vt,
                uint16_t* __restrict__ attn)
{
  __shared__ uint16_t Ps[32*1024];    // 64 KB; phase 1: [0..16K)=Qs, [16K..32K)=Ks
  __shared__ uint16_t Vs[512*64];     // 64 KB
  __shared__ float redm[4*32], redl[4*32];
  uint16_t* Qs = Ps;
  uint16_t* Ks = Ps + 32*512;

  // XCD grouping: blocks with same (blk&7) share a batch-pair -> K/V L2 reuse
  const int blk = blockIdx.x;
  const int xcd = blk & 7, idx = blk >> 3;
  const int b = xcd*2 + (idx >> 5);
  const int q0 = (idx & 31) * 32;

  const int t = threadIdx.x;
  const int lane = t & 63, w = t >> 6;
  const int quad = lane >> 4, lm = lane & 15;
  const float scale = 0.044194173824159216f; // 512^-0.5

  const uint16_t* qb  = qk + (size_t)b*S_*1024;       // [1024 rows][1024] (Q|K)
  const uint16_t* Vtb = Vt + (size_t)b*C_*S_;         // [512][1024] k-major

  // ---- stage Q strip (32x512) ----
  #pragma unroll
  for(int i=0;i<8;i++){
    const int l = i*256 + t;
    gload16(qb + (size_t)(q0 + (l>>6))*1024 + (l&63)*8, Qs + l*8);
  }

  // ---- phase 1: S = Q K^T ----
  f32x4 acc_s[2][8][2];
  #pragma unroll
  for(int ii=0;ii<2;ii++)
    #pragma unroll
    for(int nc=0;nc<8;nc++)
      #pragma unroll
      for(int jj=0;jj<2;jj++) acc_s[ii][nc][jj] = (f32x4){0.f,0.f,0.f,0.f};

  #pragma unroll
  for(int nc=0;nc<8;nc++){
    #pragma unroll
    for(int k0=0;k0<512;k0+=128){
      #pragma unroll
      for(int i=0;i<8;i++){
        const int l = i*256 + t;
        gload16(qb + (size_t)(nc*128 + (l>>4))*1024 + 512 + k0 + (l&15)*8, Ks + l*8);
      }
      __syncthreads();
      #pragma unroll
      for(int kk=0;kk<128;kk+=32){
        bf16x8 av[2], bv[2];
        #pragma unroll
        for(int ii=0;ii<2;ii++) av[ii] = *(const bf16x8*)&Qs[(ii*16+lm)*512 + k0 + kk + quad*8];
        #pragma unroll
        for(int jj=0;jj<2;jj++) bv[jj] = *(const bf16x8*)&Ks[(w*32 + jj*16 + lm)*128 + kk + quad*8];
        #pragma unroll
        for(int ii=0;ii<2;ii++)
          #pragma unroll
          for(int jj=0;jj<2;jj++)
            acc_s[ii][nc][jj] = __builtin_amdgcn_mfma_f32_16x16x32_bf16(av[ii], bv[jj], acc_s[ii][nc][jj], 0,0,0);
      }
      __syncthreads();
    }
  }

  // ---- phase 2: exact softmax over each of 32 rows ----
  // lane's rows: row = ii*16 + quad*4 + rr
  float mrow[2][4], rcpl[2][4];
  #pragma unroll
  for(int ii=0;ii<2;ii++)
    #pragma unroll
    for(int rr=0;rr<4;rr++){
      float m = -3.4e38f;
      #pragma unroll
      for(int nc=0;nc<8;nc++)
        #pragma unroll
        for(int jj=0;jj<2;jj++) m = fmaxf(m, acc_s[ii][nc][jj][rr]);
      #pragma unroll
      for(int o=1;o<16;o<<=1) m = fmaxf(m, __shfl_xor(m,o,64));
      mrow[ii][rr] = m;
      if (lm==0) redm[w*32 + ii*16 + (quad<<2) + rr] = m;
    }
  __syncthreads();
  #pragma unroll
  for(int ii=0;ii<2;ii++)
    #pragma unroll
    for(int rr=0;rr<4;rr++){
      const int row = ii*16 + (quad<<2) + rr;
      float m = fmaxf(fmaxf(redm[row], redm[32+row]), fmaxf(redm[64+row], redm[96+row]));
      mrow[ii][rr] = m;
      float s = 0.f;
      #pragma unroll
      for(int nc=0;nc<8;nc++)
        #pragma unroll
        for(int jj=0;jj<2;jj++){
          float e = __expf((acc_s[ii][nc][jj][rr] - m)*scale);
          acc_s[ii][nc][jj][rr] = e;
          s += e;
        }
      #pragma unroll
      for(int o=1;o<16;o<<=1) s += __shfl_xor(s,o,64);
      rcpl[ii][rr] = s;   // partial (this wave); finalize after LDS combine
      if (lm==0) redl[w*32 + row] = s;
    }
  __syncthreads();
  #pragma unroll
  for(int ii=0;ii<2;ii++)
    #pragma unroll
    for(int rr=0;rr<4;rr++){
      const int row = ii*16 + (quad<<2) + rr;
      rcpl[ii][rr] = 1.f/(redl[row] + redl[32+row] + redl[64+row] + redl[96+row]);
    }
  // write P (unscaled exp) to LDS, overwriting Qs/Ks
  #pragma unroll
  for(int ii=0;ii<2;ii++)
    #pragma unroll
    for(int rr=0;rr<4;rr++){
      const int row = ii*16 + (quad<<2) + rr;
      #pragma unroll
      for(int nc=0;nc<8;nc++)
        #pragma unroll
        for(int jj=0;jj<2;jj++)
          Ps[row*1024 + nc*128 + w*32 + jj*16 + lm] = f2bf(acc_s[ii][nc][jj][rr]);
    }
  __syncthreads();

  // ---- phase 3: O = P V  (inner k = 1024 key positions, BK=64) ----
  f32x4 acc_o[2][8];
  #pragma unroll
  for(int ii=0;ii<2;ii++)
    #pragma unroll
    for(int jc=0;jc<8;jc++) acc_o[ii][jc] = (f32x4){0.f,0.f,0.f,0.f};

  for(int kc=0;kc<16;kc++){
    #pragma unroll
    for(int i=0;i<16;i++){
      const int l = i*256 + t;
      gload16(Vtb + (size_t)(l>>3)*1024 + kc*64 + (l&7)*8, Vs + l*8);
    }
    __syncthreads();
    #pragma unroll
    for(int kk=0;kk<64;kk+=32){
      bf16x8 av[2], bv[8];
      #pragma unroll
      for(int ii=0;ii<2;ii++) av[ii] = *(const bf16x8*)&Ps[(ii*16+lm)*1024 + kc*64 + kk + quad*8];
      #pragma unroll
      for(int jc=0;jc<8;jc++) bv[jc] = *(const bf16x8*)&Vs[(w*128 + jc*16 + lm)*64 + kk + quad*8];
      #pragma unroll
      for(int ii=0;ii<2;ii++)
        #pragma unroll
        for(int jc=0;jc<8;jc++)
          acc_o[ii][jc] = __builtin_amdgcn_mfma_f32_16x16x32_bf16(av[ii], bv[jc], acc_o[ii][jc], 0,0,0);
    }
    __syncthreads();
  }

  // ---- epilogue: attn[b*1024+q][c] = O * (1/l) ----
  #pragma unroll
  for(int ii=0;ii<2;ii++)
    #pragma unroll
    for(int rr=0;rr<4;rr++){
      const int qg = b*S_ + q0 + ii*16 + (quad<<2) + rr;
      const float rl = rcpl[ii][rr];
      #pragma unroll
      for(int jc=0;jc<8;jc++)
        attn[(size_t)qg*512 + w*128 + jc*16 + lm] = f2bf(acc_o[ii][jc][rr] * rl);
    }
}

extern "C" void kernel_launch(void* const* d_in, const int* in_sizes, int n_in,
                              void* d_out, int out_size, void* d_ws, size_t ws_size,
                              hipStream_t stream){
  char* ws = (char*)d_ws;
  int*      flag  = (int*)ws;
  float2*   part  = (float2*)(ws + 4096);
  uint16_t* gnwb  = (uint16_t*)(ws + 16384);
  uint16_t* gnbb  = (uint16_t*)(ws + 17408);
  uint16_t* qkvbb = (uint16_t*)(ws + 18432);
  uint16_t* projbb= (uint16_t*)(ws + 21504);
  uint16_t* qkvwb = (uint16_t*)(ws + 32768);          // 1.57 MB
  uint16_t* projwb= (uint16_t*)(ws + 1605632);        // 0.52 MB
  uint16_t* xb    = (uint16_t*)(ws + 4194304);        // 16.8 MB [B,C,S]
  uint16_t* hT    = (uint16_t*)(ws + 20971520);       // 16.8 MB [16384,512]; reused for attn out
  uint16_t* qk    = (uint16_t*)(ws + 37748736);       // 33.6 MB [16384,1024] (Q|K)
  uint16_t* Vt    = (uint16_t*)(ws + 71303168);       // 16.8 MB [16,512,1024]
  // end ~88 MB

  hipLaunchKernelGGL(detect_k, dim3(1), dim3(256), 0, stream,
                     (const uint16_t*)d_in[0], flag);
  hipLaunchKernelGGL(param_conv, dim3(513), dim3(256), 0, stream,
                     d_in[3], d_in[5], d_in[1], d_in[2], d_in[4], d_in[6],
                     qkvwb, projwb, gnwb, gnbb, qkvbb, projbb, flag);
  hipLaunchKernelGGL(conv_x_gn, dim3(1024), dim3(256), 0, stream, d_in[0], xb, part, flag);
  hipLaunchKernelGGL(gn_apply_t, dim3(16,8,16), dim3(256), 0, stream, xb, gnwb, gnbb, part, hT);

  // QK: [16384,512] x [1024,512]^T -> qk[16384,1024] (+bias cols 0..1023)
  hipLaunchKernelGGL((gemm_bt<true,false,false,false>), dim3(8,128,1), dim3(256), 0, stream,
      hT, qkvwb, (void*)qk, qkvbb, (const uint16_t*)nullptr, flag,
      512, 512, 1024, 512, 0LL, 0LL, 0LL);

  // V^T: per batch [512,512] x [1024,512]^T -> Vt[b][512,1024] (+bias rows 1024..1535)
  hipLaunchKernelGGL((gemm_bt<true,true,false,false>), dim3(8,4,16), dim3(256), 0, stream,
      qkvwb + (size_t)1024*512, hT, (void*)Vt, qkvbb + 1024, (const uint16_t*)nullptr, flag,
      512, 512, 1024, 512, 0LL, (long long)S_*C_, (long long)C_*S_);

  // fused attention: scores+softmax+PV -> hT[bs,512]
  hipLaunchKernelGGL(attn_fused, dim3(512), dim3(256), 0, stream, qk, Vt, hT);

  // out[b,c,s] = projW · attn_b^T + projb + x
  hipLaunchKernelGGL((gemm_bt<true,true,true,true>), dim3(8,4,16), dim3(256), 0, stream,
      projwb, hT, d_out, projbb, xb, flag,
      512, 512, 1024, 512, 0LL, (long long)S_*C_, (long long)C_*S_);
}

// Round 5
// 265.289 us; speedup vs baseline: 1.4204x; 1.4204x over previous
//
#include <hip/hip_runtime.h>
#include <stdint.h>

#define B_  16
#define C_  512
#define S_  1024
#define NSAMP (C_*S_)

typedef __bf16 bf16x8 __attribute__((ext_vector_type(8)));
typedef float  f32x4  __attribute__((ext_vector_type(4)));

__device__ __forceinline__ float bf2f(uint16_t u){ return __uint_as_float(((uint32_t)u)<<16); }
__device__ __forceinline__ uint16_t f2bf(float f){
  uint32_t u = __float_as_uint(f);
  uint32_t r = u + 0x7fffu + ((u>>16)&1u);   // RNE
  return (uint16_t)(r>>16);
}
__device__ __forceinline__ float wsum(float v){
  #pragma unroll
  for(int o=32;o;o>>=1) v += __shfl_xor(v,o,64);
  return v;
}
__device__ __forceinline__ float wmax(float v){
  #pragma unroll
  for(int o=32;o;o>>=1) v = fmaxf(v, __shfl_xor(v,o,64));
  return v;
}
__device__ __forceinline__ void gload16(const void* g, void* l){
  __builtin_amdgcn_global_load_lds(
      (__attribute__((address_space(1))) void*)g,
      (__attribute__((address_space(3))) void*)l, 16, 0, 0);
}

// ---------- dtype detector ----------
__global__ __launch_bounds__(256) void detect_k(const uint16_t* __restrict__ x,
                                                int* __restrict__ flag){
  __shared__ int sh[4];
  int cnt = 0;
  for(int i=threadIdx.x; i<32768; i+=256){
    uint32_t e = (x[2*i] >> 7) & 0xffu;
    cnt += (e >= 132) ? 1 : 0;
  }
  #pragma unroll
  for(int o=32;o;o>>=1) cnt += __shfl_xor(cnt,o,64);
  const int lane = threadIdx.x & 63, w = threadIdx.x >> 6;
  if (lane==0) sh[w] = cnt;
  __syncthreads();
  if (threadIdx.x==0) *flag = (sh[0]+sh[1]+sh[2]+sh[3] > 4096) ? 1 : 0;  // 1 => fp32
}

// ---------- fused: x -> bf16 copy + GN partial sums ----------
__global__ __launch_bounds__(256) void conv_x_gn(const void* __restrict__ src,
                                                 uint16_t* __restrict__ xb,
                                                 float2* __restrict__ part,
                                                 const int* __restrict__ flag){
  const int f = *flag;
  const size_t base = (size_t)blockIdx.x * 8192;
  float s = 0.f, s2 = 0.f;
  if (f){
    const float4* sp = (const float4*)((const float*)src + base);
    ushort4* dp = (ushort4*)(xb + base);
    #pragma unroll
    for(int i=0;i<8;i++){
      float4 v = sp[i*256 + threadIdx.x];
      s  += v.x + v.y + v.z + v.w;
      s2 += v.x*v.x + v.y*v.y + v.z*v.z + v.w*v.w;
      ushort4 o; o.x=f2bf(v.x); o.y=f2bf(v.y); o.z=f2bf(v.z); o.w=f2bf(v.w);
      dp[i*256 + threadIdx.x] = o;
    }
  } else {
    const uint4* sp = (const uint4*)((const uint16_t*)src + base);
    uint4* dp = (uint4*)(xb + base);
    #pragma unroll
    for(int i=0;i<4;i++){
      uint4 p = sp[i*256 + threadIdx.x];
      dp[i*256 + threadIdx.x] = p;
      uint32_t uu[4] = {p.x,p.y,p.z,p.w};
      #pragma unroll
      for(int q=0;q<4;q++){
        float f0 = __uint_as_float(uu[q]<<16);
        float f1 = __uint_as_float(uu[q] & 0xffff0000u);
        s += f0 + f1; s2 += f0*f0 + f1*f1;
      }
    }
  }
  s = wsum(s); s2 = wsum(s2);
  __shared__ float rs[4], rq[4];
  const int lane = threadIdx.x & 63, w = threadIdx.x >> 6;
  if (lane==0){ rs[w]=s; rq[w]=s2; }
  __syncthreads();
  if (threadIdx.x==0)
    part[blockIdx.x] = make_float2(rs[0]+rs[1]+rs[2]+rs[3], rq[0]+rq[1]+rq[2]+rq[3]);
}

// ---------- all params -> bf16 copies ----------
__device__ __forceinline__ void convseg(const void* src, uint16_t* dst, int n, int f, int t){
  const int idx = t*8;
  if (idx >= n) return;
  if (f){
    const float* s = (const float*)src;
    float4 v0 = *(const float4*)(s + idx);
    float4 v1 = *(const float4*)(s + idx + 4);
    ushort4 a, b;
    a.x=f2bf(v0.x); a.y=f2bf(v0.y); a.z=f2bf(v0.z); a.w=f2bf(v0.w);
    b.x=f2bf(v1.x); b.y=f2bf(v1.y); b.z=f2bf(v1.z); b.w=f2bf(v1.w);
    *(ushort4*)(dst + idx)     = a;
    *(ushort4*)(dst + idx + 4) = b;
  } else {
    *(uint4*)(dst + idx) = *(const uint4*)((const uint16_t*)src + idx);
  }
}
__global__ __launch_bounds__(256) void param_conv(
    const void* qkvw, const void* projw, const void* gnw, const void* gnb,
    const void* qkvb, const void* projb,
    uint16_t* qkvwb, uint16_t* projwb, uint16_t* gnwb, uint16_t* gnbb,
    uint16_t* qkvbb, uint16_t* projbb, const int* __restrict__ flag){
  const int f = *flag;
  const int bid = blockIdx.x, t = threadIdx.x;
  if (bid < 384){
    const size_t off = (size_t)bid*2048;
    convseg((const char*)qkvw + off*(f?4:2), qkvwb + off, 2048, f, t);
  } else if (bid < 512){
    const size_t off = (size_t)(bid-384)*2048;
    convseg((const char*)projw + off*(f?4:2), projwb + off, 2048, f, t);
  } else {
    convseg(gnw,   gnwb,   512,  f, t);
    convseg(gnb,   gnbb,   512,  f, t);
    convseg(qkvb,  qkvbb,  1536, f, t);
    convseg(projb, projbb, 512,  f, t);
  }
}

// ---- GN apply + transpose [B,C,S] -> hT [B,S,C] bf16 ----
__global__ __launch_bounds__(256) void gn_apply_t(const uint16_t* __restrict__ x,
    const uint16_t* __restrict__ gw, const uint16_t* __restrict__ gb,
    const float2* __restrict__ part, uint16_t* __restrict__ hT){
  __shared__ float tile[64][65];
  const int b = blockIdx.z, c0 = blockIdx.y<<6, s0 = blockIdx.x<<6;
  const int tc = threadIdx.x >> 6, tl = threadIdx.x & 63;
  float2 p = part[b*64 + tl];
  float s = wsum(p.x), s2 = wsum(p.y);
  const float ninv = 1.f/(float)NSAMP;
  const float mn = s*ninv;
  const float rstd = rsqrtf(s2*ninv - mn*mn + 1e-5f);
  #pragma unroll
  for(int r=0;r<16;r++){
    int cl = r*4 + tc;
    tile[cl][tl] = bf2f(x[((size_t)b*C_ + c0+cl)*S_ + s0 + tl]);
  }
  __syncthreads();
  const float wv = bf2f(gw[c0+tl]) * rstd;
  const float bv = bf2f(gb[c0+tl]);
  #pragma unroll
  for(int r=0;r<16;r++){
    int sl = r*4 + tc;
    float v = (tile[tl][sl] - mn)*wv + bv;
    hT[((size_t)b*S_ + s0+sl)*C_ + c0 + tl] = f2bf(v);
  }
}

// ---------------- 128x128 MFMA GEMM, C = A * Bt^T ----------------
// SWZMODE 0: blocks sharing an A row-tile (all bx, fixed by/bz) -> same XCD.
// SWZMODE 1: blocks sharing a  B row-tile (all by, fixed bx/bz) -> same XCD.
// LDS XOR swizzle: 16B granule g of row r stored at granule g^(r&7); applied on
// the global-address side of global_load_lds, fragment reads are single granules.
template<bool HASBIAS, bool BIASROW, bool OUTDYN, bool HASRES, int SWZMODE>
__global__ __launch_bounds__(256)
void gemm_bt(const uint16_t* __restrict__ A, const uint16_t* __restrict__ Bt,
             void* __restrict__ Cp, const uint16_t* __restrict__ bias,
             const uint16_t* __restrict__ xres, const int* __restrict__ flag,
             int lda, int ldb, int ldc, int K,
             long long sA, long long sB, long long sC)
{
  __shared__ uint16_t As[128*64];
  __shared__ uint16_t Bs[128*64];
  const int lin = (blockIdx.z * gridDim.y + blockIdx.y) * gridDim.x + blockIdx.x;
  const int r8 = lin & 7, kk8 = lin >> 3;
  int bx, by, bz;
  if (SWZMODE == 0){
    const int G = (gridDim.y * gridDim.z) >> 3;     // groups per XCD
    const int g = r8 * G + (kk8 % G);
    bx = kk8 / G; by = g % gridDim.y; bz = g / gridDim.y;
  } else {
    const int G = (gridDim.x * gridDim.z) >> 3;
    const int g = r8 * G + (kk8 % G);
    by = kk8 / G; bx = g % gridDim.x; bz = g / gridDim.x;
  }

  const int tid = threadIdx.x;
  const int lane = tid & 63, w = tid >> 6;
  const int quad = lane >> 4, lm = lane & 15;
  const int m0 = by << 7, n0 = bx << 7;
  A  += (size_t)bz * sA;
  Bt += (size_t)bz * sB;

  f32x4 acc[4][4];
  #pragma unroll
  for(int i=0;i<4;i++)
    #pragma unroll
    for(int j=0;j<4;j++) acc[i][j] = (f32x4){0.f,0.f,0.f,0.f};

  const int wm = (w & 1) << 6, wn = (w >> 1) << 6;
  const int srow = tid >> 3;                       // 0..31 staged row
  const int sx   = (tid & 7) ^ (srow & 7);         // XOR-swizzled k-granule
  const uint16_t* ga = A  + (size_t)(m0 + srow)*lda + sx*8;
  const uint16_t* gb = Bt + (size_t)(n0 + srow)*ldb + sx*8;
  uint16_t* sa = &As[tid*8];
  uint16_t* sb = &Bs[tid*8];

  for(int k0=0;k0<K;k0+=64){
    #pragma unroll
    for(int i=0;i<4;i++){
      gload16(ga + (size_t)(i*32)*lda + k0, sa + i*2048);
      gload16(gb + (size_t)(i*32)*ldb + k0, sb + i*2048);
    }
    __syncthreads();
    #pragma unroll
    for(int kk=0;kk<64;kk+=32){
      bf16x8 av[4], bv[4];
      #pragma unroll
      for(int i=0;i<4;i++){
        const int row = wm + i*16 + lm;
        av[i] = *(const bf16x8*)&As[row*64 + ((((kk>>3)+quad) ^ (row&7))<<3)];
      }
      #pragma unroll
      for(int j=0;j<4;j++){
        const int row = wn + j*16 + lm;
        bv[j] = *(const bf16x8*)&Bs[row*64 + ((((kk>>3)+quad) ^ (row&7))<<3)];
      }
      #pragma unroll
      for(int i=0;i<4;i++)
        #pragma unroll
        for(int j=0;j<4;j++)
          acc[i][j] = __builtin_amdgcn_mfma_f32_16x16x32_bf16(av[i], bv[j], acc[i][j], 0,0,0);
    }
    __syncthreads();
  }

  const int f = OUTDYN ? *flag : 0;
  const size_t cb = (size_t)bz * (size_t)sC;
  #pragma unroll
  for(int j=0;j<4;j++){
    const int col = n0 + wn + j*16 + lm;
    const float cbias = (HASBIAS && !BIASROW) ? bf2f(bias[col]) : 0.f;
    #pragma unroll
    for(int i=0;i<4;i++){
      const int rb = m0 + wm + i*16 + (quad<<2);
      #pragma unroll
      for(int r=0;r<4;r++){
        const int row = rb + r;
        float v = acc[i][j][r] + cbias;
        if (HASBIAS && BIASROW) v += bf2f(bias[row]);
        const size_t idx = cb + (size_t)row*ldc + col;
        if (HASRES) v += bf2f(xres[idx]);
        if (OUTDYN && f) ((float*)Cp)[idx] = v;
        else             ((uint16_t*)Cp)[idx] = f2bf(v);
      }
    }
  }
}

// ---- softmax over bf16 score rows, in place ----
__global__ __launch_bounds__(256) void softmax_k(uint16_t* __restrict__ sc){
  uint16_t* srow = sc + (size_t)blockIdx.x * 1024;
  const int t = threadIdx.x, lane = t & 63, w = t >> 6;
  __shared__ float red[4];
  ushort4 v = ((const ushort4*)srow)[t];
  const float scale = 0.044194173824159216f; // 512^-0.5
  float a = bf2f(v.x)*scale, b = bf2f(v.y)*scale, c = bf2f(v.z)*scale, d = bf2f(v.w)*scale;
  float mx = fmaxf(fmaxf(a,b),fmaxf(c,d));
  mx = wmax(mx);
  if (lane==0) red[w] = mx;
  __syncthreads();
  mx = fmaxf(fmaxf(red[0],red[1]),fmaxf(red[2],red[3]));
  float e0=__expf(a-mx), e1=__expf(b-mx), e2=__expf(c-mx), e3=__expf(d-mx);
  float s = wsum(e0+e1+e2+e3);
  __syncthreads();
  if (lane==0) red[w] = s;
  __syncthreads();
  const float inv = 1.f/(red[0]+red[1]+red[2]+red[3]);
  ushort4 o;
  o.x = f2bf(e0*inv); o.y = f2bf(e1*inv); o.z = f2bf(e2*inv); o.w = f2bf(e3*inv);
  ((ushort4*)srow)[t] = o;
}

extern "C" void kernel_launch(void* const* d_in, const int* in_sizes, int n_in,
                              void* d_out, int out_size, void* d_ws, size_t ws_size,
                              hipStream_t stream){
  char* ws = (char*)d_ws;
  int*      flag  = (int*)ws;
  float2*   part  = (float2*)(ws + 4096);
  uint16_t* gnwb  = (uint16_t*)(ws + 16384);
  uint16_t* gnbb  = (uint16_t*)(ws + 17408);
  uint16_t* qkvbb = (uint16_t*)(ws + 18432);
  uint16_t* projbb= (uint16_t*)(ws + 21504);
  uint16_t* qkvwb = (uint16_t*)(ws + 32768);          // 1.57 MB
  uint16_t* projwb= (uint16_t*)(ws + 1605632);        // 0.52 MB
  uint16_t* xb    = (uint16_t*)(ws + 4194304);        // 16.8 MB [B,C,S]
  uint16_t* hT    = (uint16_t*)(ws + 20971520);       // 16.8 MB [16384,512]; reused for attn
  uint16_t* qk    = (uint16_t*)(ws + 37748736);       // 33.6 MB [16384,1024] (Q|K)
  uint16_t* sc    = (uint16_t*)(ws + 71303168);       // 33.6 MB [16,1024,1024]
  uint16_t* Vt    = (uint16_t*)(ws + 104857600);      // 16.8 MB [16,512,1024]
  // end ~121.6 MB

  hipLaunchKernelGGL(detect_k, dim3(1), dim3(256), 0, stream,
                     (const uint16_t*)d_in[0], flag);
  hipLaunchKernelGGL(param_conv, dim3(513), dim3(256), 0, stream,
                     d_in[3], d_in[5], d_in[1], d_in[2], d_in[4], d_in[6],
                     qkvwb, projwb, gnwb, gnbb, qkvbb, projbb, flag);
  hipLaunchKernelGGL(conv_x_gn, dim3(1024), dim3(256), 0, stream, d_in[0], xb, part, flag);
  hipLaunchKernelGGL(gn_apply_t, dim3(16,8,16), dim3(256), 0, stream, xb, gnwb, gnbb, part, hT);

  // QK: [16384,512] x [1024,512]^T -> qk[16384,1024] (+bias cols 0..1023)
  hipLaunchKernelGGL((gemm_bt<true,false,false,false,0>), dim3(8,128,1), dim3(256), 0, stream,
      hT, qkvwb, (void*)qk, qkvbb, (const uint16_t*)nullptr, flag,
      512, 512, 1024, 512, 0LL, 0LL, 0LL);

  // V^T: per batch Vw[512,512] x hT_b[1024,512]^T -> Vt[b][512,1024] (+bias rows 1024..1535)
  hipLaunchKernelGGL((gemm_bt<true,true,false,false,1>), dim3(8,4,16), dim3(256), 0, stream,
      qkvwb + (size_t)1024*512, hT, (void*)Vt, qkvbb + 1024, (const uint16_t*)nullptr, flag,
      512, 512, 1024, 512, 0LL, (long long)S_*C_, (long long)C_*S_);

  // scores = Q K^T (bf16), per batch: [1024,512] x [1024,512]^T
  hipLaunchKernelGGL((gemm_bt<false,false,false,false,0>), dim3(8,8,16), dim3(256), 0, stream,
      qk, qk + 512, (void*)sc, (const uint16_t*)nullptr, (const uint16_t*)nullptr, flag,
      1024, 1024, 1024, 512, (long long)S_*1024, (long long)S_*1024, (long long)S_*S_);

  hipLaunchKernelGGL(softmax_k, dim3(B_*S_), dim3(256), 0, stream, sc);

  // attn = P V: per batch [1024,1024] x [512,1024]^T -> hT[bs,512]
  hipLaunchKernelGGL((gemm_bt<false,false,false,false,0>), dim3(4,8,16), dim3(256), 0, stream,
      sc, Vt, (void*)hT, (const uint16_t*)nullptr, (const uint16_t*)nullptr, flag,
      1024, 1024, 512, 1024, (long long)S_*S_, (long long)C_*S_, (long long)S_*C_);

  // out[b,c,s] = projW · attn_b^T + projb + x
  hipLaunchKernelGGL((gemm_bt<true,true,true,true,1>), dim3(8,4,16), dim3(256), 0, stream,
      projwb, hT, d_out, projbb, xb, flag,
      512, 512, 1024, 512, 0LL, (long long)S_*C_, (long long)C_*S_);
}

// Round 6
// 244.231 us; speedup vs baseline: 1.5429x; 1.0862x over previous
//
#include <hip/hip_runtime.h>
#include <stdint.h>

#define B_  16
#define C_  512
#define S_  1024
#define NSAMP (C_*S_)

typedef __bf16 bf16x8 __attribute__((ext_vector_type(8)));
typedef float  f32x4  __attribute__((ext_vector_type(4)));

__device__ __forceinline__ float bf2f(uint16_t u){ return __uint_as_float(((uint32_t)u)<<16); }
__device__ __forceinline__ uint16_t f2bf(float f){
  uint32_t u = __float_as_uint(f);
  uint32_t r = u + 0x7fffu + ((u>>16)&1u);   // RNE
  return (uint16_t)(r>>16);
}
__device__ __forceinline__ float wsum(float v){
  #pragma unroll
  for(int o=32;o;o>>=1) v += __shfl_xor(v,o,64);
  return v;
}
__device__ __forceinline__ void gload16(const void* g, void* l){
  __builtin_amdgcn_global_load_lds(
      (__attribute__((address_space(1))) void*)g,
      (__attribute__((address_space(3))) void*)l, 16, 0, 0);
}

// ---------- dtype detector ----------
__global__ __launch_bounds__(256) void detect_k(const uint16_t* __restrict__ x,
                                                int* __restrict__ flag){
  __shared__ int sh[4];
  int cnt = 0;
  for(int i=threadIdx.x; i<32768; i+=256){
    uint32_t e = (x[2*i] >> 7) & 0xffu;
    cnt += (e >= 132) ? 1 : 0;
  }
  #pragma unroll
  for(int o=32;o;o>>=1) cnt += __shfl_xor(cnt,o,64);
  const int lane = threadIdx.x & 63, w = threadIdx.x >> 6;
  if (lane==0) sh[w] = cnt;
  __syncthreads();
  if (threadIdx.x==0) *flag = (sh[0]+sh[1]+sh[2]+sh[3] > 4096) ? 1 : 0;  // 1 => fp32
}

// ---------- merged prep: x->bf16 + GN partials (blocks 0..1023) | params->bf16 (1024..1536) ----------
__device__ __forceinline__ void convseg(const void* src, uint16_t* dst, int n, int f, int t){
  const int idx = t*8;
  if (idx >= n) return;
  if (f){
    const float* s = (const float*)src;
    float4 v0 = *(const float4*)(s + idx);
    float4 v1 = *(const float4*)(s + idx + 4);
    ushort4 a, b;
    a.x=f2bf(v0.x); a.y=f2bf(v0.y); a.z=f2bf(v0.z); a.w=f2bf(v0.w);
    b.x=f2bf(v1.x); b.y=f2bf(v1.y); b.z=f2bf(v1.z); b.w=f2bf(v1.w);
    *(ushort4*)(dst + idx)     = a;
    *(ushort4*)(dst + idx + 4) = b;
  } else {
    *(uint4*)(dst + idx) = *(const uint4*)((const uint16_t*)src + idx);
  }
}
__global__ __launch_bounds__(256) void prep_k(
    const void* __restrict__ srcx, uint16_t* __restrict__ xb, float2* __restrict__ part,
    const void* qkvw, const void* projw, const void* gnw, const void* gnb,
    const void* qkvb, const void* projb,
    uint16_t* qkvwb, uint16_t* projwb, uint16_t* gnwb, uint16_t* gnbb,
    uint16_t* qkvbb, uint16_t* projbb, const int* __restrict__ flag){
  const int f = *flag;
  const int t = threadIdx.x;
  if (blockIdx.x >= 1024){
    const int bid = blockIdx.x - 1024;
    if (bid < 384){
      const size_t off = (size_t)bid*2048;
      convseg((const char*)qkvw + off*(f?4:2), qkvwb + off, 2048, f, t);
    } else if (bid < 512){
      const size_t off = (size_t)(bid-384)*2048;
      convseg((const char*)projw + off*(f?4:2), projwb + off, 2048, f, t);
    } else {
      convseg(gnw,   gnwb,   512,  f, t);
      convseg(gnb,   gnbb,   512,  f, t);
      convseg(qkvb,  qkvbb,  1536, f, t);
      convseg(projb, projbb, 512,  f, t);
    }
    return;
  }
  const size_t base = (size_t)blockIdx.x * 8192;
  float s = 0.f, s2 = 0.f;
  if (f){
    const float4* sp = (const float4*)((const float*)srcx + base);
    ushort4* dp = (ushort4*)(xb + base);
    #pragma unroll
    for(int i=0;i<8;i++){
      float4 v = sp[i*256 + t];
      s  += v.x + v.y + v.z + v.w;
      s2 += v.x*v.x + v.y*v.y + v.z*v.z + v.w*v.w;
      ushort4 o; o.x=f2bf(v.x); o.y=f2bf(v.y); o.z=f2bf(v.z); o.w=f2bf(v.w);
      dp[i*256 + t] = o;
    }
  } else {
    const uint4* sp = (const uint4*)((const uint16_t*)srcx + base);
    uint4* dp = (uint4*)(xb + base);
    #pragma unroll
    for(int i=0;i<4;i++){
      uint4 p = sp[i*256 + t];
      dp[i*256 + t] = p;
      uint32_t uu[4] = {p.x,p.y,p.z,p.w};
      #pragma unroll
      for(int q=0;q<4;q++){
        float f0 = __uint_as_float(uu[q]<<16);
        float f1 = __uint_as_float(uu[q] & 0xffff0000u);
        s += f0 + f1; s2 += f0*f0 + f1*f1;
      }
    }
  }
  s = wsum(s); s2 = wsum(s2);
  __shared__ float rs[4], rq[4];
  const int lane = t & 63, w = t >> 6;
  if (lane==0){ rs[w]=s; rq[w]=s2; }
  __syncthreads();
  if (t==0)
    part[blockIdx.x] = make_float2(rs[0]+rs[1]+rs[2]+rs[3], rq[0]+rq[1]+rq[2]+rq[3]);
}

// ---- GN apply + transpose [B,C,S] -> hT [B,S,C] bf16 ----
__global__ __launch_bounds__(256) void gn_apply_t(const uint16_t* __restrict__ x,
    const uint16_t* __restrict__ gw, const uint16_t* __restrict__ gb,
    const float2* __restrict__ part, uint16_t* __restrict__ hT){
  __shared__ float tile[64][65];
  const int b = blockIdx.z, c0 = blockIdx.y<<6, s0 = blockIdx.x<<6;
  const int tc = threadIdx.x >> 6, tl = threadIdx.x & 63;
  float2 p = part[b*64 + tl];
  float s = wsum(p.x), s2 = wsum(p.y);
  const float ninv = 1.f/(float)NSAMP;
  const float mn = s*ninv;
  const float rstd = rsqrtf(s2*ninv - mn*mn + 1e-5f);
  #pragma unroll
  for(int r=0;r<16;r++){
    int cl = r*4 + tc;
    tile[cl][tl] = bf2f(x[((size_t)b*C_ + c0+cl)*S_ + s0 + tl]);
  }
  __syncthreads();
  const float wv = bf2f(gw[c0+tl]) * rstd;
  const float bv = bf2f(gb[c0+tl]);
  #pragma unroll
  for(int r=0;r<16;r++){
    int sl = r*4 + tc;
    float v = (tile[tl][sl] - mn)*wv + bv;
    hT[((size_t)b*S_ + s0+sl)*C_ + c0 + tl] = f2bf(v);
  }
}

// ======== merged QK + V^T GEMMs (both read hT, K=512, lda=ldb=512) ========
// blocks 0..1023:  qk[row,col] = hT · qkvw[0:1024]^T + qkvb[col]
// blocks 1024..1535: Vt[b][ch,key] = Vw · hT_b^T + qkvb[1024+ch]
__global__ __launch_bounds__(256)
void qkv_k(const uint16_t* __restrict__ hT, const uint16_t* __restrict__ qkvw,
           const uint16_t* __restrict__ qkvb, uint16_t* __restrict__ qk,
           uint16_t* __restrict__ Vt)
{
  __shared__ uint16_t As[128*64];
  __shared__ uint16_t Bs[128*64];
  const int tid = threadIdx.x;
  const int lane = tid & 63, w = tid >> 6;
  const int quad = lane >> 4, lm = lane & 15;
  const int wm = (w & 1) << 6, wn = (w >> 1) << 6;

  const bool vpath = blockIdx.x >= 1024;
  const int id = vpath ? (blockIdx.x - 1024) : blockIdx.x;
  const int r8 = id & 7, k8 = id >> 3;
  int m0, n0, bz;
  const uint16_t *Abase, *Bbase;
  if (!vpath){
    const int g = r8*16 + (k8 & 15);        // by 0..127
    m0 = g << 7; n0 = (k8 >> 4) << 7; bz = 0;
    Abase = hT + (size_t)m0*512;
    Bbase = qkvw + (size_t)n0*512;
  } else {
    const int g = r8*16 + (k8 & 15);        // 0..127 -> (bx,bz)
    m0 = (k8 >> 4) << 7; n0 = (g & 7) << 7; bz = g >> 3;
    Abase = qkvw + (size_t)(1024 + m0)*512;
    Bbase = hT + (size_t)bz*S_*C_ + (size_t)n0*512;
  }

  f32x4 acc[4][4];
  #pragma unroll
  for(int i=0;i<4;i++)
    #pragma unroll
    for(int j=0;j<4;j++) acc[i][j] = (f32x4){0.f,0.f,0.f,0.f};

  const int srow = tid >> 3;
  const int sx   = (tid & 7) ^ (srow & 7);
  const uint16_t* ga = Abase + (size_t)srow*512 + sx*8;
  const uint16_t* gb = Bbase + (size_t)srow*512 + sx*8;
  uint16_t* sa = &As[tid*8];
  uint16_t* sb = &Bs[tid*8];

  for(int k0=0;k0<512;k0+=64){
    #pragma unroll
    for(int i=0;i<4;i++){
      gload16(ga + (size_t)(i*32)*512 + k0, sa + i*2048);
      gload16(gb + (size_t)(i*32)*512 + k0, sb + i*2048);
    }
    __syncthreads();
    #pragma unroll
    for(int kk=0;kk<64;kk+=32){
      bf16x8 av[4], bv[4];
      #pragma unroll
      for(int i=0;i<4;i++){
        const int row = wm + i*16 + lm;
        av[i] = *(const bf16x8*)&As[row*64 + ((((kk>>3)+quad) ^ (row&7))<<3)];
      }
      #pragma unroll
      for(int j=0;j<4;j++){
        const int row = wn + j*16 + lm;
        bv[j] = *(const bf16x8*)&Bs[row*64 + ((((kk>>3)+quad) ^ (row&7))<<3)];
      }
      #pragma unroll
      for(int i=0;i<4;i++)
        #pragma unroll
        for(int j=0;j<4;j++)
          acc[i][j] = __builtin_amdgcn_mfma_f32_16x16x32_bf16(av[i], bv[j], acc[i][j], 0,0,0);
    }
    __syncthreads();
  }

  if (!vpath){
    #pragma unroll
    for(int j=0;j<4;j++){
      const int col = n0 + wn + j*16 + lm;
      const float bvv = bf2f(qkvb[col]);
      #pragma unroll
      for(int i=0;i<4;i++){
        const int rb = m0 + wm + i*16 + (quad<<2);
        #pragma unroll
        for(int r=0;r<4;r++)
          qk[(size_t)(rb+r)*1024 + col] = f2bf(acc[i][j][r] + bvv);
      }
    }
  } else {
    uint16_t* vb = Vt + (size_t)bz*C_*S_;
    #pragma unroll
    for(int i=0;i<4;i++){
      const int rb = m0 + wm + i*16 + (quad<<2);
      #pragma unroll
      for(int r=0;r<4;r++){
        const float bvv = bf2f(qkvb[1024 + rb + r]);
        #pragma unroll
        for(int j=0;j<4;j++)
          vb[(size_t)(rb+r)*1024 + n0 + wn + j*16 + lm] = f2bf(acc[i][j][r] + bvv);
      }
    }
  }
}

// ---------------- 128x128 MFMA GEMM, C = A * Bt^T ----------------
// EXP: epilogue writes exp(scale*acc) (for scores->P', un-normalized, no max-sub).
// SUMNORM: accumulates per-row sums of A via MFMA-with-ones; epilogue divides.
template<bool HASBIAS, bool BIASROW, bool OUTDYN, bool HASRES, int SWZMODE, bool EXP, bool SUMNORM>
__global__ __launch_bounds__(256)
void gemm_bt(const uint16_t* __restrict__ A, const uint16_t* __restrict__ Bt,
             void* __restrict__ Cp, const uint16_t* __restrict__ bias,
             const uint16_t* __restrict__ xres, const int* __restrict__ flag,
             int lda, int ldb, int ldc, int K,
             long long sA, long long sB, long long sC)
{
  __shared__ uint16_t As[128*64];
  __shared__ uint16_t Bs[128*64];
  const int lin = (blockIdx.z * gridDim.y + blockIdx.y) * gridDim.x + blockIdx.x;
  const int r8 = lin & 7, kk8 = lin >> 3;
  int bx, by, bz;
  if (SWZMODE == 0){
    const int G = (gridDim.y * gridDim.z) >> 3;
    const int g = r8 * G + (kk8 % G);
    bx = kk8 / G; by = g % gridDim.y; bz = g / gridDim.y;
  } else {
    const int G = (gridDim.x * gridDim.z) >> 3;
    const int g = r8 * G + (kk8 % G);
    by = kk8 / G; bx = g % gridDim.x; bz = g / gridDim.x;
  }

  const int tid = threadIdx.x;
  const int lane = tid & 63, w = tid >> 6;
  const int quad = lane >> 4, lm = lane & 15;
  const int m0 = by << 7, n0 = bx << 7;
  A  += (size_t)bz * sA;
  Bt += (size_t)bz * sB;

  f32x4 acc[4][4];
  #pragma unroll
  for(int i=0;i<4;i++)
    #pragma unroll
    for(int j=0;j<4;j++) acc[i][j] = (f32x4){0.f,0.f,0.f,0.f};
  f32x4 rsum[4];
  bf16x8 onesv;
  if (SUMNORM){
    #pragma unroll
    for(int i=0;i<4;i++) rsum[i] = (f32x4){0.f,0.f,0.f,0.f};
    #pragma unroll
    for(int z=0;z<8;z++) onesv[z] = (__bf16)1.0f;
  }

  const int wm = (w & 1) << 6, wn = (w >> 1) << 6;
  const int srow = tid >> 3;
  const int sx   = (tid & 7) ^ (srow & 7);
  const uint16_t* ga = A  + (size_t)(m0 + srow)*lda + sx*8;
  const uint16_t* gb = Bt + (size_t)(n0 + srow)*ldb + sx*8;
  uint16_t* sa = &As[tid*8];
  uint16_t* sb = &Bs[tid*8];

  for(int k0=0;k0<K;k0+=64){
    #pragma unroll
    for(int i=0;i<4;i++){
      gload16(ga + (size_t)(i*32)*lda + k0, sa + i*2048);
      gload16(gb + (size_t)(i*32)*ldb + k0, sb + i*2048);
    }
    __syncthreads();
    #pragma unroll
    for(int kk=0;kk<64;kk+=32){
      bf16x8 av[4], bv[4];
      #pragma unroll
      for(int i=0;i<4;i++){
        const int row = wm + i*16 + lm;
        av[i] = *(const bf16x8*)&As[row*64 + ((((kk>>3)+quad) ^ (row&7))<<3)];
      }
      #pragma unroll
      for(int j=0;j<4;j++){
        const int row = wn + j*16 + lm;
        bv[j] = *(const bf16x8*)&Bs[row*64 + ((((kk>>3)+quad) ^ (row&7))<<3)];
      }
      #pragma unroll
      for(int i=0;i<4;i++){
        if (SUMNORM) rsum[i] = __builtin_amdgcn_mfma_f32_16x16x32_bf16(av[i], onesv, rsum[i], 0,0,0);
        #pragma unroll
        for(int j=0;j<4;j++)
          acc[i][j] = __builtin_amdgcn_mfma_f32_16x16x32_bf16(av[i], bv[j], acc[i][j], 0,0,0);
      }
    }
    __syncthreads();
  }

  const int f = OUTDYN ? *flag : 0;
  const size_t cb = (size_t)bz * (size_t)sC;
  #pragma unroll
  for(int j=0;j<4;j++){
    const int col = n0 + wn + j*16 + lm;
    const float cbias = (HASBIAS && !BIASROW) ? bf2f(bias[col]) : 0.f;
    #pragma unroll
    for(int i=0;i<4;i++){
      const int rb = m0 + wm + i*16 + (quad<<2);
      #pragma unroll
      for(int r=0;r<4;r++){
        const int row = rb + r;
        float v = acc[i][j][r] + cbias;
        if (HASBIAS && BIASROW) v += bf2f(bias[row]);
        if (EXP)     v = __expf(v * 0.044194173824159216f);   // 512^-0.5
        if (SUMNORM) v = v / rsum[i][r];
        const size_t idx = cb + (size_t)row*ldc + col;
        if (HASRES) v += bf2f(xres[idx]);
        if (OUTDYN && f) ((float*)Cp)[idx] = v;
        else             ((uint16_t*)Cp)[idx] = f2bf(v);
      }
    }
  }
}

extern "C" void kernel_launch(void* const* d_in, const int* in_sizes, int n_in,
                              void* d_out, int out_size, void* d_ws, size_t ws_size,
                              hipStream_t stream){
  char* ws = (char*)d_ws;
  int*      flag  = (int*)ws;
  float2*   part  = (float2*)(ws + 4096);
  uint16_t* gnwb  = (uint16_t*)(ws + 16384);
  uint16_t* gnbb  = (uint16_t*)(ws + 17408);
  uint16_t* qkvbb = (uint16_t*)(ws + 18432);
  uint16_t* projbb= (uint16_t*)(ws + 21504);
  uint16_t* qkvwb = (uint16_t*)(ws + 32768);          // 1.57 MB
  uint16_t* projwb= (uint16_t*)(ws + 1605632);        // 0.52 MB
  uint16_t* xb    = (uint16_t*)(ws + 4194304);        // 16.8 MB [B,C,S]
  uint16_t* hT    = (uint16_t*)(ws + 20971520);       // 16.8 MB [16384,512]; reused for attn
  uint16_t* qk    = (uint16_t*)(ws + 37748736);       // 33.6 MB [16384,1024] (Q|K)
  uint16_t* sc    = (uint16_t*)(ws + 71303168);       // 33.6 MB [16,1024,1024] P'
  uint16_t* Vt    = (uint16_t*)(ws + 104857600);      // 16.8 MB [16,512,1024]
  // end ~121.6 MB

  hipLaunchKernelGGL(detect_k, dim3(1), dim3(256), 0, stream,
                     (const uint16_t*)d_in[0], flag);
  hipLaunchKernelGGL(prep_k, dim3(1537), dim3(256), 0, stream,
                     d_in[0], xb, part,
                     d_in[3], d_in[5], d_in[1], d_in[2], d_in[4], d_in[6],
                     qkvwb, projwb, gnwb, gnbb, qkvbb, projbb, flag);
  hipLaunchKernelGGL(gn_apply_t, dim3(16,8,16), dim3(256), 0, stream, xb, gnwb, gnbb, part, hT);

  // merged QK + V^T
  hipLaunchKernelGGL(qkv_k, dim3(1536), dim3(256), 0, stream, hT, qkvwb, qkvbb, qk, Vt);

  // P' = exp(scale * Q K^T) (bf16), per batch
  hipLaunchKernelGGL((gemm_bt<false,false,false,false,0,true,false>), dim3(8,8,16), dim3(256), 0, stream,
      qk, qk + 512, (void*)sc, (const uint16_t*)nullptr, (const uint16_t*)nullptr, flag,
      1024, 1024, 1024, 512, (long long)S_*1024, (long long)S_*1024, (long long)S_*S_);

  // attn = (P' V) / rowsum(P'): per batch [1024,1024] x [512,1024]^T -> hT[bs,512]
  hipLaunchKernelGGL((gemm_bt<false,false,false,false,0,false,true>), dim3(4,8,16), dim3(256), 0, stream,
      sc, Vt, (void*)hT, (const uint16_t*)nullptr, (const uint16_t*)nullptr, flag,
      1024, 1024, 512, 1024, (long long)S_*S_, (long long)C_*S_, (long long)S_*C_);

  // out[b,c,s] = projW · attn_b^T + projb + x
  hipLaunchKernelGGL((gemm_bt<true,true,true,true,1,false,false>), dim3(8,4,16), dim3(256), 0, stream,
      projwb, hT, d_out, projbb, xb, flag,
      512, 512, 1024, 512, 0LL, (long long)S_*C_, (long long)C_*S_);
}